// Round 15
// baseline (123.387 us; speedup 1.0000x reference)
//
#include <hip/hip_runtime.h>
#include <stdint.h>

// Problem constants (fixed by reference)
#define NB 32    // batch
#define NC 64    // input channels
#define NH 64
#define NW 64
#define NO 512   // output channels
#define HP 66    // h-padded rows (1 zero row top+bottom)
// xh layout: [NB][66 hp][64 w][64 c] bf16, hp 0/65 zero rows, swizzled:
//   16B chunk (c>>3) of col w stored at chunk slot ((c>>3) ^ (w&7)).

typedef __bf16 bf16x8 __attribute__((ext_vector_type(8)));
typedef short  s16x8  __attribute__((ext_vector_type(8)));
typedef float  f32x4  __attribute__((ext_vector_type(4)));

__device__ __forceinline__ uint16_t f2bf(float f) {
  uint32_t u = __builtin_bit_cast(uint32_t, f);
  u += 0x7fffu + ((u >> 16) & 1u);   // round-to-nearest-even
  return (uint16_t)(u >> 16);
}

// async global->LDS, 16B per lane. LDS dest = wave-uniform base + lane*16.
__device__ __forceinline__ void gld16(const uint16_t* g, uint16_t* l) {
  __builtin_amdgcn_global_load_lds(
      (const __attribute__((address_space(1))) void*)(g),
      (__attribute__((address_space(3))) void*)(l), 16, 0, 0);
}

// ---------------- kernel 1: fused prep (build_w + nhwc transpose) --------
__global__ void k_prep(const float* __restrict__ dict,
                       const float* __restrict__ coef,
                       const int*   __restrict__ idx,
                       const float* __restrict__ x,
                       uint16_t*    __restrict__ Wl,
                       uint16_t*    __restrict__ xh) {
  const int bid = blockIdx.x;
  const int t = threadIdx.x;            // 256
  if (bid < NO) {                       // ---- build_w for o = bid ----
    __shared__ float tmp[576];
    const int o = bid;
#pragma unroll
    for (int j = 0; j < 3; ++j) {
      const int id = t + j * 256;
      if (id < 576) {
        float v = 0.f;
#pragma unroll
        for (int s = 0; s < 4; ++s)
          v += coef[o * 4 + s] * dict[idx[o * 4 + s] * 576 + id];
        tmp[id] = v;
      }
    }
    __syncthreads();
#pragma unroll
    for (int j = 0; j < 3; ++j) {
      const int id = t + j * 256;
      if (id < 576) {
        const int c = id & 63, p = id >> 6;
        const int sl = ((p * NO + o) * 8 + ((c >> 3) ^ (o & 7))) * 8 + (c & 7);
        Wl[sl] = f2bf(tmp[c * 9 + p]);
      }
    }
    return;
  }
  // ---- nhwc for bh = bid - NO ----
  const int bh = bid - NO;              // b*66 + hp
  const int b = bh / HP, hp = bh % HP;
  uint16_t* row = xh + (size_t)(b * HP + hp) * 4096;
  int4* r4 = reinterpret_cast<int4*>(row);             // 512 int4
  if (hp == 0 || hp == HP - 1) {        // zero h-pad rows
    r4[t]       = int4{0, 0, 0, 0};
    r4[t + 256] = int4{0, 0, 0, 0};
    return;
  }
  __shared__ float tile[64][65];
  const int h = hp - 1;
  const int w = t & 63;
#pragma unroll
  for (int c = (t >> 6); c < 64; c += 4)
    tile[c][w] = x[((size_t)(b * NC + c) * NH + h) * NW + w];
  __syncthreads();
#pragma unroll
  for (int i = 0; i < 2; ++i) {
    const int s = t + i * 256;          // 512 slots: w2 (0..63), cb (0..7)
    const int w2 = s >> 3, cb = s & 7;
    uint32_t d[4];
#pragma unroll
    for (int j = 0; j < 4; ++j) {
      const uint32_t lo = f2bf(tile[cb * 8 + 2 * j][w2]);
      const uint32_t hi = f2bf(tile[cb * 8 + 2 * j + 1][w2]);
      d[j] = lo | (hi << 16);
    }
    r4[w2 * 8 + (cb ^ (w2 & 7))] =
        int4{(int)d[0], (int)d[1], (int)d[2], (int)d[3]};
  }
}

// ---------------- kernel 2: persistent conv, 0.29 reads/MFMA -------------
// 256 blocks (1/CU), 512 thr (8 waves). Block owns one (b, h-octet):
// xs (10 halo'd rows, 84.5 KB) staged ONCE; 4 o-rounds of 128 o.
// Wave = 64 o x 128 pix (2 h-rows): acc[8][4] f32x4 (128 VGPR).
// Per (g,q): braw[4][4] (16 reads) shared by ALL 3 dh taps + 12 af reads
// -> 28 reads / 96 MFMAs (0.29, vs 0.5 in R8/R14; LDS pipe 46->27 us).
// as = one dw-group [3 taps][128 o] (48 KB), restaged per g; round
// boundary: prefetch next round's group-0 BEFORE the 32 nt stores, then
// vmcnt(32) (waits only the 6 gld16s; stores drain under next compute).
__global__ __launch_bounds__(512, 2) void k_conv(
    const uint16_t* __restrict__ xh,   // [NB][66][64][64] bf16, pre-swizzled
    const uint16_t* __restrict__ Wl,   // [9][512][64] bf16, pre-swizzled
    const float*    __restrict__ bias,
    float*          __restrict__ out) {
  __shared__ __align__(16) uint16_t xs[10 * 66 * 64];     // 84,480 B
  __shared__ __align__(16) uint16_t as[3 * 128 * 64];     // 49,152 B

  const int t = threadIdx.x;
  const int lane = t & 63;
  const int wid  = t >> 6;      // 0..7
  const int blk = blockIdx.x;                  // 256 blocks
  // XCD-chunked: XCD k gets 32 consecutive gy (4 b's, L2-resident slice)
  const int gy = (blk & 7) * 32 + (blk >> 3);
  const int b  = gy >> 3;
  const int h0 = (gy & 7) * 8;

  // ---- zero the w-halo slots (slot 0 and 65 of each of 10 rows) ----
  if (t < 160) {
    const int r = t >> 4, sl = (t >> 3) & 1, j = t & 7;
    reinterpret_cast<int4*>(xs)[r * 528 + sl * 520 + j] = int4{0, 0, 0, 0};
  }
  // ---- stage x interior ONCE: rows 0..7 -> wave wid; rows 8,9 split ----
  {
    const uint16_t* srow = xh + (size_t)(b * HP + h0 + wid) * 4096;
    uint16_t* drow = xs + wid * 4224 + 64;     // skip w-halo slot 0
#pragma unroll
    for (int k = 0; k < 8; ++k)
      gld16(srow + k * 512 + lane * 8, drow + k * 512);
    const int r2 = 8 + (wid >> 2);
    const int kb = (wid & 3) * 2;
    const uint16_t* srow2 = xh + (size_t)(b * HP + h0 + r2) * 4096;
    uint16_t* drow2 = xs + r2 * 4224 + 64;
    gld16(srow2 + kb * 512 + lane * 8, drow2 + kb * 512);
    gld16(srow2 + (kb + 1) * 512 + lane * 8, drow2 + (kb + 1) * 512);
  }
  // ---- as staging: (orr, g) -> taps p = tap*3 + g, 128 o of round orr ----
  auto stage_a = [&](int orr, int g) {
    const int O0 = orr * 128;
#pragma unroll
    for (int j = 0; j < 6; ++j) {
      const int c = wid * 6 + j;               // 0..47
      const int tap = c >> 4, k = c & 15;      // 16 chunks per tap
      const uint16_t* src =
          Wl + (size_t)(tap * 3 + g) * 32768 + (O0 + k * 8) * 64;
      gld16(src + lane * 8, as + tap * 8192 + k * 512);
    }
  };
  stage_a(0, 0);

  const int wm  = wid & 1;      // o sub-block (64 each)
  const int wn  = wid >> 1;     // h-pair index 0..3
  const int l15 = lane & 15;
  const int lg  = lane >> 4;    // k-group

  // preload ALL bias (static per-round indexing; no mid-loop global loads)
  float bvv[4][4];
#pragma unroll
  for (int orr = 0; orr < 4; ++orr)
#pragma unroll
    for (int ob = 0; ob < 4; ++ob)
      bvv[orr][ob] = bias[orr * 128 + wm * 64 + ob * 16 + l15];

  f32x4 acc[8][4];              // [pix-frag][o-frag]

  __syncthreads();              // xs + as(0,0) resident

#pragma unroll
  for (int orr = 0; orr < 4; ++orr) {
    const int O0 = orr * 128;
#pragma unroll
    for (int pb = 0; pb < 8; ++pb)
#pragma unroll
      for (int ob = 0; ob < 4; ++ob)
        acc[pb][ob] = (f32x4){0.f, 0.f, 0.f, 0.f};

#pragma unroll
    for (int g = 0; g < 3; ++g) {
      const int dw = g - 1;
#pragma unroll
      for (int q = 0; q < 2; ++q) {
        const int cbB = (q * 4 + lg) ^ ((l15 + dw) & 7);
        const uint16_t* xb = xs + (l15 + dw + 1) * 64 + cbB * 8;
        // braw[rr][nw]: rows wn*2+rr, shared across the 3 dh taps
        bf16x8 braw[4][4];
#pragma unroll
        for (int rr = 0; rr < 4; ++rr)
#pragma unroll
          for (int nw = 0; nw < 4; ++nw)
            braw[rr][nw] = __builtin_bit_cast(bf16x8,
                *reinterpret_cast<const s16x8*>(
                    xb + (wn * 2 + rr) * 4224 + nw * 1024));
        const int cbA = (q * 4 + lg) ^ (l15 & 7);
        const uint16_t* ab = as + (wm * 64 + l15) * 64 + cbA * 8;
#pragma unroll
        for (int dh = 0; dh < 3; ++dh) {
          bf16x8 af[4];
#pragma unroll
          for (int ob = 0; ob < 4; ++ob)
            af[ob] = __builtin_bit_cast(bf16x8,
                *reinterpret_cast<const s16x8*>(
                    ab + dh * 8192 + ob * 1024));
#pragma unroll
          for (int pb = 0; pb < 8; ++pb)
#pragma unroll
            for (int ob = 0; ob < 4; ++ob)
              acc[pb][ob] = __builtin_amdgcn_mfma_f32_16x16x32_bf16(
                  braw[(pb >> 2) + dh][pb & 3], af[ob], acc[pb][ob], 0, 0, 0);
        }
      }
      if (g < 2) {
        asm volatile("s_waitcnt lgkmcnt(0)" ::: "memory");
        __builtin_amdgcn_s_barrier();    // readers done with as(g)
        stage_a(orr, g + 1);
        __syncthreads();                 // as(g+1) resident
      }
    }

    // ---- round boundary: restage-first, stores after, counted wait ----
    asm volatile("s_waitcnt lgkmcnt(0)" ::: "memory");
    __builtin_amdgcn_s_barrier();        // all waves done reading as
    if (orr < 3) stage_a(orr + 1, 0);    // 6 gld16 (oldest outstanding)
    asm volatile("" ::: "memory");
    {
      const int hb = h0 + wn * 2;
#pragma unroll
      for (int pb = 0; pb < 8; ++pb) {
#pragma unroll
        for (int ob = 0; ob < 4; ++ob) {
          const int o = O0 + wm * 64 + ob * 16 + l15;
          f32x4 v = acc[pb][ob];
          const float bv = bvv[orr][ob];
          v[0] += bv; v[1] += bv; v[2] += bv; v[3] += bv;
          float* dst = out +
              ((size_t)(b * NO + o) * NH + hb + (pb >> 2)) * NW +
              (pb & 3) * 16 + lg * 4;
          __builtin_nontemporal_store(v, reinterpret_cast<f32x4*>(dst));
        }
      }
    }
    asm volatile("" ::: "memory");
    if (orr < 3) {
      asm volatile("s_waitcnt vmcnt(32)" ::: "memory");  // 6 gld16 landed
      __builtin_amdgcn_s_barrier();      // as(orr+1, g0) resident
    }
  }
}

extern "C" void kernel_launch(void* const* d_in, const int* in_sizes, int n_in,
                              void* d_out, int out_size, void* d_ws, size_t ws_size,
                              hipStream_t stream) {
  const float* x    = (const float*)d_in[0];
  const float* dict = (const float*)d_in[1];
  const float* coef = (const float*)d_in[2];
  const float* bias = (const float*)d_in[3];
  const int*   idx  = (const int*)d_in[4];
  float* out = (float*)d_out;

  // workspace: xh = 32*66*4096*2 B = 16.5 MiB at 0; Wl 576 KiB at +18 MiB
  uint16_t* xh = (uint16_t*)d_ws;
  uint16_t* Wl = (uint16_t*)((char*)d_ws + (18u << 20));

  hipLaunchKernelGGL(k_prep, dim3(NO + NB * HP), dim3(256), 0, stream,
                     dict, coef, idx, x, Wl, xh);
  hipLaunchKernelGGL(k_conv, dim3(256), dim3(512), 0, stream,
                     xh, Wl, bias, out);
}

// Round 16
// 99.671 us; speedup vs baseline: 1.2379x; 1.2379x over previous
//
#include <hip/hip_runtime.h>
#include <stdint.h>

// Problem constants (fixed by reference)
#define NB 32    // batch
#define NC 64    // input channels
#define NH 64
#define NW 64
#define NO 512   // output channels
#define ND 256   // dictionary atoms
#define HP 66    // h-padded rows
// xh layout: [NB][66 hp][64 w][64 c] bf16, hp 0/65 zero rows, swizzled:
//   16B chunk (c>>3) of col w stored at chunk slot ((c>>3) ^ (w&7)).

typedef __bf16 bf16x8 __attribute__((ext_vector_type(8)));
typedef short  s16x8  __attribute__((ext_vector_type(8)));
typedef float  f32x4  __attribute__((ext_vector_type(4)));
typedef uint32_t u32x2 __attribute__((ext_vector_type(2)));

__device__ __forceinline__ uint16_t f2bf(float f) {
  uint32_t u = __builtin_bit_cast(uint32_t, f);
  u += 0x7fffu + ((u >> 16) & 1u);   // round-to-nearest-even
  return (uint16_t)(u >> 16);
}
__device__ __forceinline__ uint32_t pk2(float a, float b) {
  return (uint32_t)f2bf(a) | ((uint32_t)f2bf(b) << 16);
}
__device__ __forceinline__ float ubf_lo(uint32_t u) {
  return __builtin_bit_cast(float, u << 16);
}
__device__ __forceinline__ float ubf_hi(uint32_t u) {
  return __builtin_bit_cast(float, u & 0xffff0000u);
}

// async global->LDS, 16B per lane. LDS dest = wave-uniform base + lane*16.
__device__ __forceinline__ void gld16(const uint16_t* g, uint16_t* l) {
  __builtin_amdgcn_global_load_lds(
      (const __attribute__((address_space(1))) void*)(g),
      (__attribute__((address_space(3))) void*)(l), 16, 0, 0);
}

// ---------------- kernel 1: fused prep (dict->bf16 reorder + transpose) --
// bid < ND: Wd[p][d][c] = dict[d][c][p] bf16, pre-swizzled:
//   Wd[((p*ND + d)*8 + ((c>>3) ^ (d&7)))*8 + (c&7)]
// bid >= ND: x NCHW fp32 -> xh padded swizzled bf16 (verified R13-R15).
__global__ void k_prep(const float* __restrict__ dict,
                       const float* __restrict__ x,
                       uint16_t*    __restrict__ Wd,
                       uint16_t*    __restrict__ xh) {
  const int bid = blockIdx.x;
  const int t = threadIdx.x;            // 256
  if (bid < ND) {                       // ---- Wd build for d = bid ----
    const int d = bid;
#pragma unroll
    for (int j = 0; j < 3; ++j) {
      const int id = t + j * 256;
      if (id < 576) {
        const int c = id & 63, p = id >> 6;
        const int sl = ((p * ND + d) * 8 + ((c >> 3) ^ (d & 7))) * 8 + (c & 7);
        Wd[sl] = f2bf(dict[d * 576 + c * 9 + p]);
      }
    }
    return;
  }
  // ---- nhwc for bh = bid - ND ----
  const int bh = bid - ND;              // b*66 + hp
  const int b = bh / HP, hp = bh % HP;
  uint16_t* row = xh + (size_t)(b * HP + hp) * 4096;
  int4* r4 = reinterpret_cast<int4*>(row);             // 512 int4
  if (hp == 0 || hp == HP - 1) {        // zero h-pad rows
    r4[t]       = int4{0, 0, 0, 0};
    r4[t + 256] = int4{0, 0, 0, 0};
    return;
  }
  __shared__ float tile[64][65];
  const int h = hp - 1;
  const int w = t & 63;
#pragma unroll
  for (int c = (t >> 6); c < 64; c += 4)
    tile[c][w] = x[((size_t)(b * NC + c) * NH + h) * NW + w];
  __syncthreads();
#pragma unroll
  for (int i = 0; i < 2; ++i) {
    const int s = t + i * 256;          // 512 slots: w2 (0..63), cb (0..7)
    const int w2 = s >> 3, cb = s & 7;
    uint32_t dd[4];
#pragma unroll
    for (int j = 0; j < 4; ++j)
      dd[j] = pk2(tile[cb * 8 + 2 * j][w2], tile[cb * 8 + 2 * j + 1][w2]);
    r4[w2 * 8 + (cb ^ (w2 & 7))] =
        int4{(int)dd[0], (int)dd[1], (int)dd[2], (int)dd[3]};
  }
}

// ---------------- kernel 2: dictionary-conv + LDS gather-combine ---------
// 512 blocks, 512 thr (8 waves). Block = (b, h-quad): 256 pix.
// PHASE 1 (dict conv, HALF the MFMAs of W_eff form): S[256 d][256 pix] =
//   conv(x, dict) on this pixel tile. Wave = 64 d x 128 pix, acc[8][4].
//   R15's verified core: braw[4][4] shared across 3 dh taps, 28 reads /
//   96 MFMAs per (g,q); as = dw-group [3 taps][256 d] (96 KB) restaged 2x.
// S -> LDS as bf16 (128 KB overlay, XOR-swizzled rows, conflict-free).
// PHASE 2: per wave 64 o: out[o,pix] = sum_4 coef[o,s]*S[idx[o,s]][pix]
//   + bias[o]. Row gathers are wave-uniform -> lane-linear ds_read_b64;
//   lane holds 4 consecutive w -> direct f32x4 nt store.
__global__ __launch_bounds__(512, 2) void k_conv(
    const uint16_t* __restrict__ xh,   // [NB][66][64][64] bf16, pre-swizzled
    const uint16_t* __restrict__ Wd,   // [9][256][64] bf16, pre-swizzled
    const float*    __restrict__ coef, // [512][4]
    const int*      __restrict__ idx,  // [512][4], values in [0,256)
    const float*    __restrict__ bias, // [512]
    float*          __restrict__ out) {
  __shared__ __align__(16) uint16_t smem[74496];  // 148,992 B
  uint16_t* xs  = smem;            // [6][66][64] = 25,344 elems (50,688 B)
  uint16_t* asw = smem + 25344;    // [3][256][64] = 49,152 elems (98,304 B)
  uint8_t*  Sb  = (uint8_t*)smem;  // S overlay: 256 rows x 512 B = 128 KB

  const int t = threadIdx.x;
  const int lane = t & 63;
  const int wid  = t >> 6;      // 0..7
  // XCD-chunked: XCD k gets 64 consecutive s (4 b's, L2-resident slice)
  const int flat = blockIdx.x;                 // 512 blocks
  const int s    = (flat & 7) * 64 + (flat >> 3);
  const int b    = s >> 4;
  const int hq   = s & 15;                     // h-quad
  const int h0p  = hq * 4;                     // padded-row base

  // ---- zero the w-halo slots (slot 0 and 65 of each of 6 rows) ----
  if (t < 96) {
    const int r = t >> 4, sl = (t >> 3) & 1, j = t & 7;
    reinterpret_cast<int4*>(xs)[r * 528 + sl * 520 + j] = int4{0, 0, 0, 0};
  }
  // ---- stage xs: 6 rows (hp = h0p..h0p+5), 48 x 1KB chunks ----
  {
#pragma unroll
    for (int j = 0; j < 6; ++j) {
      const int ch = wid * 6 + j;              // 0..47
      const int r = ch >> 3, k = ch & 7;
      gld16(xh + (size_t)(b * HP + h0p + r) * 4096 + k * 512 + lane * 8,
            xs + r * 4224 + 64 + k * 512);
    }
  }
  // ---- as staging: group g = taps p = dh*3 + g (dh 0..2), all 256 d ----
  auto stage_a = [&](int g) {
#pragma unroll
    for (int j = 0; j < 12; ++j) {
      const int ch = wid * 12 + j;             // 0..95
      const int tap = ch >> 5, k = ch & 31;    // 32 chunks per tap
      gld16(Wd + (size_t)(tap * 3 + g) * 16384 + k * 512 + lane * 8,
            asw + tap * 16384 + k * 512);
    }
  };
  stage_a(0);

  const int wd  = wid & 3;      // d-tile (64 each)
  const int wn  = wid >> 2;     // pix half (128 each = 2 h-rows)
  const int l15 = lane & 15;
  const int lg  = lane >> 4;

  f32x4 acc[8][4];              // [pix-frag][d-frag]
#pragma unroll
  for (int pb = 0; pb < 8; ++pb)
#pragma unroll
    for (int db = 0; db < 4; ++db)
      acc[pb][db] = (f32x4){0.f, 0.f, 0.f, 0.f};

  __syncthreads();              // xs + as(g0) resident

  // ================= PHASE 1: S = conv(x, dict) =================
#pragma unroll
  for (int g = 0; g < 3; ++g) {
    const int dw = g - 1;
#pragma unroll
    for (int q = 0; q < 2; ++q) {
      const int cbB = (q * 4 + lg) ^ ((l15 + dw) & 7);
      const uint16_t* xb = xs + (l15 + dw + 1) * 64 + cbB * 8;
      bf16x8 braw[4][4];        // rows wn*2+rr, shared across 3 dh taps
#pragma unroll
      for (int rr = 0; rr < 4; ++rr)
#pragma unroll
        for (int nw = 0; nw < 4; ++nw)
          braw[rr][nw] = __builtin_bit_cast(bf16x8,
              *reinterpret_cast<const s16x8*>(
                  xb + (wn * 2 + rr) * 4224 + nw * 1024));
      const int cbA = (q * 4 + lg) ^ (l15 & 7);
      const uint16_t* ab = asw + (wd * 64 + l15) * 64 + cbA * 8;
#pragma unroll
      for (int dh = 0; dh < 3; ++dh) {
        bf16x8 af[4];
#pragma unroll
        for (int db = 0; db < 4; ++db)
          af[db] = __builtin_bit_cast(bf16x8,
              *reinterpret_cast<const s16x8*>(
                  ab + dh * 16384 + db * 1024));
#pragma unroll
        for (int pb = 0; pb < 8; ++pb)
#pragma unroll
          for (int db = 0; db < 4; ++db)
            acc[pb][db] = __builtin_amdgcn_mfma_f32_16x16x32_bf16(
                braw[(pb >> 2) + dh][pb & 3], af[db], acc[pb][db], 0, 0, 0);
      }
    }
    if (g < 2) {
      __syncthreads();          // all waves done reading as(g)
      stage_a(g + 1);
      __syncthreads();          // as(g+1) resident
    }
  }

  // ---- acc -> S (bf16, XOR-swizzled rows); overlays xs/as ----
  __syncthreads();              // all phase-1 LDS reads complete
#pragma unroll
  for (int pb = 0; pb < 8; ++pb) {
#pragma unroll
    for (int db = 0; db < 4; ++db) {
      const int d   = wd * 64 + db * 16 + l15;
      const int pix = (wn * 2 + (pb >> 2)) * 64 + (pb & 3) * 16 + lg * 4;
      u32x2 u;
      u[0] = pk2(acc[pb][db][0], acc[pb][db][1]);
      u[1] = pk2(acc[pb][db][2], acc[pb][db][3]);
      *reinterpret_cast<u32x2*>(
          Sb + d * 512 + ((pix * 2) ^ ((d & 7) << 4))) = u;
    }
  }
  __syncthreads();              // S fully resident

  // ================= PHASE 2: gather-combine =================
  const int hrow = lane >> 4;          // 0..3 within quad
  const int wcol = (lane & 15) * 4;    // 4 consecutive w per lane
#pragma unroll 4
  for (int oo = 0; oo < 64; ++oo) {
    const int o = wid * 64 + oo;
    const int4 iv = *reinterpret_cast<const int4*>(idx + o * 4);
    const f32x4 cv = *reinterpret_cast<const f32x4*>(coef + o * 4);
    const float bv = bias[o];
    f32x4 v = {bv, bv, bv, bv};
#define GATH(ROW, CS) do {                                                  \
      const int r_ = (ROW);                                                 \
      const u32x2 u_ = *reinterpret_cast<const u32x2*>(                     \
          Sb + r_ * 512 + ((lane * 8) ^ ((r_ & 7) << 4)));                  \
      const float c_ = (CS);                                                \
      v[0] += c_ * ubf_lo(u_[0]);  v[1] += c_ * ubf_hi(u_[0]);              \
      v[2] += c_ * ubf_lo(u_[1]);  v[3] += c_ * ubf_hi(u_[1]);              \
    } while (0)
    GATH(iv.x, cv[0]);
    GATH(iv.y, cv[1]);
    GATH(iv.z, cv[2]);
    GATH(iv.w, cv[3]);
#undef GATH
    float* dst = out + ((size_t)(b * NO + o) * NH + hq * 4 + hrow) * NW + wcol;
    __builtin_nontemporal_store(v, reinterpret_cast<f32x4*>(dst));
  }
}

extern "C" void kernel_launch(void* const* d_in, const int* in_sizes, int n_in,
                              void* d_out, int out_size, void* d_ws, size_t ws_size,
                              hipStream_t stream) {
  const float* x    = (const float*)d_in[0];
  const float* dict = (const float*)d_in[1];
  const float* coef = (const float*)d_in[2];
  const float* bias = (const float*)d_in[3];
  const int*   idx  = (const int*)d_in[4];
  float* out = (float*)d_out;

  // workspace: xh = 32*66*4096*2 B = 16.5 MiB at 0; Wd 288 KiB at +18 MiB
  uint16_t* xh = (uint16_t*)d_ws;
  uint16_t* Wd = (uint16_t*)((char*)d_ws + (18u << 20));

  hipLaunchKernelGGL(k_prep, dim3(ND + NB * HP), dim3(256), 0, stream,
                     dict, x, Wd, xh);
  hipLaunchKernelGGL(k_conv, dim3(512), dim3(512), 0, stream,
                     xh, Wd, coef, idx, bias, out);
}